// Round 7
// baseline (160.762 us; speedup 1.0000x reference)
//
#include <hip/hip_runtime.h>
#include <math.h>

#define BATCH 4
#define SEQ   4096
#define DIM   1024
#define VEC   4

typedef float f32x4 __attribute__((ext_vector_type(4)));

// Per-d parameters: a = phazor = p/|p| * exp(-|p|), b = phazor_init.
__device__ __forceinline__ void load_params4(
    const float* __restrict__ phr, const float* __restrict__ phi,
    const float* __restrict__ pir, const float* __restrict__ pii,
    int d0, float* ar, float* ai, float* br, float* bi)
{
    float4 p_r = *reinterpret_cast<const float4*>(phr + d0);
    float4 p_i = *reinterpret_cast<const float4*>(phi + d0);
    float4 q_r = *reinterpret_cast<const float4*>(pir + d0);
    float4 q_i = *reinterpret_cast<const float4*>(pii + d0);
    float prv[VEC] = {p_r.x, p_r.y, p_r.z, p_r.w};
    float piv[VEC] = {p_i.x, p_i.y, p_i.z, p_i.w};
    float qrv[VEC] = {q_r.x, q_r.y, q_r.z, q_r.w};
    float qiv[VEC] = {q_i.x, q_i.y, q_i.z, q_i.w};
#pragma unroll
    for (int j = 0; j < VEC; ++j) {
        float mag = sqrtf(prv[j] * prv[j] + piv[j] * piv[j]);
        float s = expf(-mag) / mag;
        ar[j] = prv[j] * s;
        ai[j] = piv[j] * s;
        br[j] = qrv[j];
        bi[j] = qiv[j];
    }
}

// K1: per-chunk local scan with zero initial state -> chunk carries.
// Grid (NC, BATCH) blocks of 256 threads; (256,4) -> <=128 VGPR, 4 blocks/CU.
template <int NC>
__global__ __launch_bounds__(256, 4) void k1_carry(
    const float* __restrict__ x,
    const float* __restrict__ phr, const float* __restrict__ phi,
    const float* __restrict__ pir, const float* __restrict__ pii,
    float2* __restrict__ carry)
{
    constexpr int S = SEQ / NC;
    const int d0 = threadIdx.x * VEC;
    const int c = blockIdx.x, b = blockIdx.y;

    float ar[VEC], ai[VEC], br[VEC], bi[VEC];
    load_params4(phr, phi, pir, pii, d0, ar, ai, br, bi);

    const float* xp = x + ((size_t)b * SEQ + (size_t)c * S) * DIM + d0;
    float Cr[VEC] = {0.f, 0.f, 0.f, 0.f};
    float Ci[VEC] = {0.f, 0.f, 0.f, 0.f};
#pragma unroll 4
    for (int t = 0; t < S; ++t) {
        float4 xv = *reinterpret_cast<const float4*>(xp + (size_t)t * DIM);
        float xa[VEC] = {xv.x, xv.y, xv.z, xv.w};
#pragma unroll
        for (int j = 0; j < VEC; ++j) {
            float nr = fmaf(ar[j], Cr[j], fmaf(-ai[j], Ci[j], br[j] * xa[j]));
            float ni = fmaf(ar[j], Ci[j], fmaf( ai[j], Cr[j], bi[j] * xa[j]));
            Cr[j] = nr; Ci[j] = ni;
        }
    }
    f32x4* cp = reinterpret_cast<f32x4*>(carry + ((size_t)b * NC + c) * DIM + d0);
    cp[0] = f32x4{Cr[0], Ci[0], Cr[1], Ci[1]};
    cp[1] = f32x4{Cr[2], Ci[2], Cr[3], Ci[3]};
}

// K2: exact per-(b,d) prefix over the NC carries, seeded with hidden.
// 4096 threads = 64 blocks x 64 (1 wave/CU on 64 CUs). Carry loads batched
// TILE=16 (independent within a tile -> few serial L2 round-trip batches).
template <int NC>
__global__ __launch_bounds__(64) void k_prefix(
    const float* __restrict__ phr, const float* __restrict__ phi,
    const float* __restrict__ hr,  const float* __restrict__ hi_,
    const float2* __restrict__ carry,
    float2* __restrict__ prefix)
{
    constexpr int S = SEQ / NC;
    const int idx = blockIdx.x * 64 + threadIdx.x;  // b*DIM + d
    const int b = idx >> 10, d = idx & (DIM - 1);

    float pr = phr[d], pi = phi[d];
    float mag = sqrtf(pr * pr + pi * pi);
    float sc = expf(-mag) / mag;
    float ASr = pr * sc, ASi = pi * sc;
    // AS = a^S via repeated squaring (S is a power of two)
#pragma unroll
    for (int e = S; e > 1; e >>= 1) {
        float nr = ASr * ASr - ASi * ASi;
        ASi = 2.f * ASr * ASi;
        ASr = nr;
    }

    float Pr = hr[idx], Pi = hi_[idx];
    const float2* cb = carry  + (size_t)b * NC * DIM + d;
    float2*       pp = prefix + (size_t)b * NC * DIM + d;
    constexpr int TILE = 16;
    static_assert(NC % TILE == 0, "NC must be a multiple of TILE");
    for (int base = 0; base < NC; base += TILE) {
        float2 cv[TILE];
#pragma unroll
        for (int k = 0; k < TILE; ++k)
            cv[k] = cb[(size_t)(base + k) * DIM];
#pragma unroll
        for (int k = 0; k < TILE; ++k) {
            pp[(size_t)(base + k) * DIM] = make_float2(Pr, Pi);
            float nr = fmaf(ASr, Pr, fmaf(-ASi, Pi, cv[k].x));
            float ni = fmaf(ASr, Pi, fmaf( ASi, Pr, cv[k].y));
            Pr = nr; Pi = ni;
        }
    }
}

// K3: seed from prefix, stream x (L3/L2-hot after K1; same grid shape keeps
// block->XCD mapping aligned with K1), NT-store out. Full unroll -> all S
// x-row loads in flight per thread.
template <int NC, bool CPLX>
__global__ __launch_bounds__(256, 4) void k_out(
    const float* __restrict__ x,
    const float* __restrict__ phr, const float* __restrict__ phi,
    const float* __restrict__ pir, const float* __restrict__ pii,
    const float2* __restrict__ prefix,
    float* __restrict__ out)
{
    constexpr int S = SEQ / NC;
    const int d0 = threadIdx.x * VEC;
    const int c = blockIdx.x, b = blockIdx.y;

    // issue seed load first (longest-latency independent load)
    const f32x4* sp =
        reinterpret_cast<const f32x4*>(prefix + ((size_t)b * NC + c) * DIM + d0);
    f32x4 s0 = sp[0], s1 = sp[1];

    float ar[VEC], ai[VEC], bqr[VEC], bqi[VEC];
    load_params4(phr, phi, pir, pii, d0, ar, ai, bqr, bqi);

    float Cr[VEC], Ci[VEC];
    Cr[0] = s0.x; Ci[0] = s0.y; Cr[1] = s0.z; Ci[1] = s0.w;
    Cr[2] = s1.x; Ci[2] = s1.y; Cr[3] = s1.z; Ci[3] = s1.w;

    const float* xp = x + ((size_t)b * SEQ + (size_t)c * S) * DIM + d0;
    const size_t obase = ((size_t)b * SEQ + (size_t)c * S) * DIM + d0;
#pragma unroll
    for (int t = 0; t < S; ++t) {
        float4 xv = *reinterpret_cast<const float4*>(xp + (size_t)t * DIM);
        float xa[VEC] = {xv.x, xv.y, xv.z, xv.w};
#pragma unroll
        for (int j = 0; j < VEC; ++j) {
            float nr = fmaf(ar[j], Cr[j], fmaf(-ai[j], Ci[j], bqr[j] * xa[j]));
            float ni = fmaf(ar[j], Ci[j], fmaf( ai[j], Cr[j], bqi[j] * xa[j]));
            Cr[j] = nr; Ci[j] = ni;
        }
        if (CPLX) {
            f32x4* dst = reinterpret_cast<f32x4*>(out + 2 * (obase + (size_t)t * DIM));
            __builtin_nontemporal_store(f32x4{Cr[0], Ci[0], Cr[1], Ci[1]}, dst);
            __builtin_nontemporal_store(f32x4{Cr[2], Ci[2], Cr[3], Ci[3]}, dst + 1);
        } else {
            __builtin_nontemporal_store(
                f32x4{Cr[0], Cr[1], Cr[2], Cr[3]},
                reinterpret_cast<f32x4*>(out + obase + (size_t)t * DIM));
        }
    }
}

// Scratch-free fallback: one thread per (b,d), serial scan over all of SEQ.
template <bool CPLX>
__global__ void k_serial(
    const float* __restrict__ x,
    const float* __restrict__ phr, const float* __restrict__ phi,
    const float* __restrict__ pir, const float* __restrict__ pii,
    const float* __restrict__ hr,  const float* __restrict__ hi_,
    float* __restrict__ out)
{
    const int idx = blockIdx.x * blockDim.x + threadIdx.x;  // b*DIM + d
    if (idx >= BATCH * DIM) return;
    const int b = idx / DIM, d = idx % DIM;

    float pr = phr[d], pi = phi[d];
    float mag = sqrtf(pr * pr + pi * pi);
    float sc = expf(-mag) / mag;
    float ar = pr * sc, ai = pi * sc;
    float br = pir[d], bi = pii[d];

    float Cr = hr[idx], Ci = hi_[idx];
    const float* xp = x + (size_t)b * SEQ * DIM + d;
    for (int t = 0; t < SEQ; ++t) {
        float xv = xp[(size_t)t * DIM];
        float nr = fmaf(ar, Cr, fmaf(-ai, Ci, br * xv));
        float ni = fmaf(ar, Ci, fmaf( ai, Cr, bi * xv));
        Cr = nr; Ci = ni;
        size_t o = ((size_t)b * SEQ + t) * DIM + d;
        if (CPLX) {
            reinterpret_cast<float2*>(out)[o] = make_float2(Cr, Ci);
        } else {
            out[o] = Cr;
        }
    }
}

template <int NC, bool CPLX>
static void run_all(const float* x, const float* hr, const float* hi_,
                    const float* phr, const float* phi,
                    const float* pir, const float* pii,
                    float* out, void* d_ws, hipStream_t stream)
{
    float2* carry  = (float2*)d_ws;
    float2* prefix = carry + (size_t)BATCH * NC * DIM;
    dim3 blk(256);
    dim3 g(NC, BATCH);
    k1_carry<NC><<<g, blk, 0, stream>>>(x, phr, phi, pir, pii, carry);
    k_prefix<NC><<<dim3(BATCH * DIM / 64), dim3(64), 0, stream>>>(
        phr, phi, hr, hi_, carry, prefix);
    k_out<NC, CPLX><<<g, blk, 0, stream>>>(
        x, phr, phi, pir, pii, prefix, out);
}

template <bool CPLX>
static void dispatch(const float* x, const float* hr, const float* hi_,
                     const float* phr, const float* phi,
                     const float* pir, const float* pii,
                     float* out, void* d_ws, size_t ws_size, hipStream_t stream)
{
    // ws need: carries + prefixes = 2 * B * NC * DIM * 8 bytes
    auto need = [](int nc) { return (size_t)2 * BATCH * nc * DIM * sizeof(float2); };
    if (ws_size >= need(512))
        run_all<512, CPLX>(x, hr, hi_, phr, phi, pir, pii, out, d_ws, stream);
    else if (ws_size >= need(256))
        run_all<256, CPLX>(x, hr, hi_, phr, phi, pir, pii, out, d_ws, stream);
    else if (ws_size >= need(128))
        run_all<128, CPLX>(x, hr, hi_, phr, phi, pir, pii, out, d_ws, stream);
    else
        k_serial<CPLX><<<dim3((BATCH * DIM + 255) / 256), dim3(256), 0, stream>>>(
            x, phr, phi, pir, pii, hr, hi_, out);
}

extern "C" void kernel_launch(void* const* d_in, const int* in_sizes, int n_in,
                              void* d_out, int out_size, void* d_ws, size_t ws_size,
                              hipStream_t stream) {
    const float* x   = (const float*)d_in[0];
    const float* hr  = (const float*)d_in[1];
    const float* hi_ = (const float*)d_in[2];
    const float* phr = (const float*)d_in[3];
    const float* phi = (const float*)d_in[4];
    const float* pir = (const float*)d_in[5];
    const float* pii = (const float*)d_in[6];
    float* out = (float*)d_out;

    const size_t total = (size_t)BATCH * SEQ * DIM;
    // out_size >= 2*total  -> buffer holds interleaved complex64 (re,im pairs)
    // otherwise            -> buffer holds exactly total floats: write real part
    if ((size_t)out_size >= 2 * total)
        dispatch<true >(x, hr, hi_, phr, phi, pir, pii, out, d_ws, ws_size, stream);
    else
        dispatch<false>(x, hr, hi_, phr, phi, pir, pii, out, d_ws, ws_size, stream);
}

// Round 8
// 147.598 us; speedup vs baseline: 1.0892x; 1.0892x over previous
//
#include <hip/hip_runtime.h>
#include <math.h>

#define BATCH 4
#define SEQ   4096
#define DIM   1024
#define VEC   4

// 3-kernel chunked scan: NCC chunks of SCC rows; exact fine-grained prefix.
// NC=256 is the measured optimum (R6: 147.7 µs total; NC=512 regressed to
// 160.8, redundant-seed variants 160-197, lookback/coop catastrophes).
#define NCC 256
#define SCC (SEQ / NCC)   // 16

typedef float f32x4 __attribute__((ext_vector_type(4)));

// Per-d parameters: a = phazor = p/|p| * exp(-|p|), b = phazor_init.
__device__ __forceinline__ void load_params4(
    const float* __restrict__ phr, const float* __restrict__ phi,
    const float* __restrict__ pir, const float* __restrict__ pii,
    int d0, float* ar, float* ai, float* br, float* bi)
{
    float4 p_r = *reinterpret_cast<const float4*>(phr + d0);
    float4 p_i = *reinterpret_cast<const float4*>(phi + d0);
    float4 q_r = *reinterpret_cast<const float4*>(pir + d0);
    float4 q_i = *reinterpret_cast<const float4*>(pii + d0);
    float prv[VEC] = {p_r.x, p_r.y, p_r.z, p_r.w};
    float piv[VEC] = {p_i.x, p_i.y, p_i.z, p_i.w};
    float qrv[VEC] = {q_r.x, q_r.y, q_r.z, q_r.w};
    float qiv[VEC] = {q_i.x, q_i.y, q_i.z, q_i.w};
#pragma unroll
    for (int j = 0; j < VEC; ++j) {
        float mag = sqrtf(prv[j] * prv[j] + piv[j] * piv[j]);
        float s = expf(-mag) / mag;
        ar[j] = prv[j] * s;
        ai[j] = piv[j] * s;
        br[j] = qrv[j];
        bi[j] = qiv[j];
    }
}

// K1: per-chunk local scan with zero initial state -> chunk carries.
// Grid (NCC, BATCH) = 1024 blocks of 256 threads; (256,4) -> 4 blocks/CU.
__global__ __launch_bounds__(256, 4) void k1_carry(
    const float* __restrict__ x,
    const float* __restrict__ phr, const float* __restrict__ phi,
    const float* __restrict__ pir, const float* __restrict__ pii,
    float2* __restrict__ carry)
{
    const int d0 = threadIdx.x * VEC;
    const int c = blockIdx.x, b = blockIdx.y;

    float ar[VEC], ai[VEC], br[VEC], bi[VEC];
    load_params4(phr, phi, pir, pii, d0, ar, ai, br, bi);

    const float* xp = x + ((size_t)b * SEQ + (size_t)c * SCC) * DIM + d0;
    float Cr[VEC] = {0.f, 0.f, 0.f, 0.f};
    float Ci[VEC] = {0.f, 0.f, 0.f, 0.f};
#pragma unroll 4
    for (int t = 0; t < SCC; ++t) {
        float4 xv = *reinterpret_cast<const float4*>(xp + (size_t)t * DIM);
        float xa[VEC] = {xv.x, xv.y, xv.z, xv.w};
#pragma unroll
        for (int j = 0; j < VEC; ++j) {
            float nr = fmaf(ar[j], Cr[j], fmaf(-ai[j], Ci[j], br[j] * xa[j]));
            float ni = fmaf(ar[j], Ci[j], fmaf( ai[j], Cr[j], bi[j] * xa[j]));
            Cr[j] = nr; Ci[j] = ni;
        }
    }
    f32x4* cp = reinterpret_cast<f32x4*>(carry + ((size_t)b * NCC + c) * DIM + d0);
    cp[0] = f32x4{Cr[0], Ci[0], Cr[1], Ci[1]};
    cp[1] = f32x4{Cr[2], Ci[2], Cr[3], Ci[3]};
}

// K2: exact per-(b,d) prefix over the NCC carries, seeded with hidden.
// 4096 threads = 64 blocks x 64 (1 wave/CU on 64 CUs). Carry loads batched
// TILE=8 (independent within a tile -> one L2 roundtrip per tile, not per k).
__global__ __launch_bounds__(64) void k_prefix(
    const float* __restrict__ phr, const float* __restrict__ phi,
    const float* __restrict__ hr,  const float* __restrict__ hi_,
    const float2* __restrict__ carry,
    float2* __restrict__ prefix)
{
    const int idx = blockIdx.x * 64 + threadIdx.x;  // b*DIM + d
    const int b = idx >> 10, d = idx & (DIM - 1);

    float pr = phr[d], pi = phi[d];
    float mag = sqrtf(pr * pr + pi * pi);
    float sc = expf(-mag) / mag;
    float a1r = pr * sc, a1i = pi * sc;

    // AS = a^SCC (SCC=16 -> 4 squarings)
    float ASr = a1r, ASi = a1i;
#pragma unroll
    for (int k = 0; k < 4; ++k) {
        float nr = ASr * ASr - ASi * ASi;
        ASi = 2.f * ASr * ASi;
        ASr = nr;
    }

    float Pr = hr[idx], Pi = hi_[idx];
    const float2* cb = carry  + (size_t)b * NCC * DIM + d;
    float2*       pp = prefix + (size_t)b * NCC * DIM + d;
    constexpr int TILE = 8;
    for (int base = 0; base < NCC; base += TILE) {
        float2 cv[TILE];
#pragma unroll
        for (int k = 0; k < TILE; ++k)
            cv[k] = cb[(size_t)(base + k) * DIM];
#pragma unroll
        for (int k = 0; k < TILE; ++k) {
            pp[(size_t)(base + k) * DIM] = make_float2(Pr, Pi);
            float nr = fmaf(ASr, Pr, fmaf(-ASi, Pi, cv[k].x));
            float ni = fmaf(ASr, Pi, fmaf( ASi, Pr, cv[k].y));
            Pr = nr; Pi = ni;
        }
    }
}

// K3: seed from prefix (exact -- no per-block seed recompute), stream x
// (L3-hot after K1, same grid shape keeps block->XCD mapping aligned),
// NT-store out (never re-read).
template <bool CPLX>
__global__ __launch_bounds__(256, 4) void k_out(
    const float* __restrict__ x,
    const float* __restrict__ phr, const float* __restrict__ phi,
    const float* __restrict__ pir, const float* __restrict__ pii,
    const float2* __restrict__ prefix,
    float* __restrict__ out)
{
    const int d0 = threadIdx.x * VEC;
    const int c = blockIdx.x, b = blockIdx.y;

    // issue seed load first (longest-latency independent load)
    const f32x4* sp =
        reinterpret_cast<const f32x4*>(prefix + ((size_t)b * NCC + c) * DIM + d0);
    f32x4 s0 = sp[0], s1 = sp[1];

    float ar[VEC], ai[VEC], bqr[VEC], bqi[VEC];
    load_params4(phr, phi, pir, pii, d0, ar, ai, bqr, bqi);

    float Cr[VEC], Ci[VEC];
    Cr[0] = s0.x; Ci[0] = s0.y; Cr[1] = s0.z; Ci[1] = s0.w;
    Cr[2] = s1.x; Ci[2] = s1.y; Cr[3] = s1.z; Ci[3] = s1.w;

    const float* xp = x + ((size_t)b * SEQ + (size_t)c * SCC) * DIM + d0;
    const size_t obase = ((size_t)b * SEQ + (size_t)c * SCC) * DIM + d0;
#pragma unroll 4
    for (int t = 0; t < SCC; ++t) {
        float4 xv = *reinterpret_cast<const float4*>(xp + (size_t)t * DIM);
        float xa[VEC] = {xv.x, xv.y, xv.z, xv.w};
#pragma unroll
        for (int j = 0; j < VEC; ++j) {
            float nr = fmaf(ar[j], Cr[j], fmaf(-ai[j], Ci[j], bqr[j] * xa[j]));
            float ni = fmaf(ar[j], Ci[j], fmaf( ai[j], Cr[j], bqi[j] * xa[j]));
            Cr[j] = nr; Ci[j] = ni;
        }
        if (CPLX) {
            f32x4* dst = reinterpret_cast<f32x4*>(out + 2 * (obase + (size_t)t * DIM));
            __builtin_nontemporal_store(f32x4{Cr[0], Ci[0], Cr[1], Ci[1]}, dst);
            __builtin_nontemporal_store(f32x4{Cr[2], Ci[2], Cr[3], Ci[3]}, dst + 1);
        } else {
            __builtin_nontemporal_store(
                f32x4{Cr[0], Cr[1], Cr[2], Cr[3]},
                reinterpret_cast<f32x4*>(out + obase + (size_t)t * DIM));
        }
    }
}

// Scratch-free fallback: one thread per (b,d), serial scan over all of SEQ.
template <bool CPLX>
__global__ void k_serial(
    const float* __restrict__ x,
    const float* __restrict__ phr, const float* __restrict__ phi,
    const float* __restrict__ pir, const float* __restrict__ pii,
    const float* __restrict__ hr,  const float* __restrict__ hi_,
    float* __restrict__ out)
{
    const int idx = blockIdx.x * blockDim.x + threadIdx.x;  // b*DIM + d
    if (idx >= BATCH * DIM) return;
    const int b = idx / DIM, d = idx % DIM;

    float pr = phr[d], pi = phi[d];
    float mag = sqrtf(pr * pr + pi * pi);
    float sc = expf(-mag) / mag;
    float ar = pr * sc, ai = pi * sc;
    float br = pir[d], bi = pii[d];

    float Cr = hr[idx], Ci = hi_[idx];
    const float* xp = x + (size_t)b * SEQ * DIM + d;
    for (int t = 0; t < SEQ; ++t) {
        float xv = xp[(size_t)t * DIM];
        float nr = fmaf(ar, Cr, fmaf(-ai, Ci, br * xv));
        float ni = fmaf(ar, Ci, fmaf( ai, Cr, bi * xv));
        Cr = nr; Ci = ni;
        size_t o = ((size_t)b * SEQ + t) * DIM + d;
        if (CPLX) {
            reinterpret_cast<float2*>(out)[o] = make_float2(Cr, Ci);
        } else {
            out[o] = Cr;
        }
    }
}

template <bool CPLX>
static void dispatch(const float* x, const float* hr, const float* hi_,
                     const float* phr, const float* phi,
                     const float* pir, const float* pii,
                     float* out, void* d_ws, size_t ws_size, hipStream_t stream)
{
    // ws: carries (8 MiB) + prefixes (8 MiB)
    const size_t need = (size_t)2 * BATCH * NCC * DIM * sizeof(float2);
    if (ws_size >= need) {
        float2* carry  = (float2*)d_ws;
        float2* prefix = carry + (size_t)BATCH * NCC * DIM;
        dim3 blk(256);
        dim3 g(NCC, BATCH);
        k1_carry<<<g, blk, 0, stream>>>(x, phr, phi, pir, pii, carry);
        k_prefix<<<dim3(BATCH * DIM / 64), dim3(64), 0, stream>>>(
            phr, phi, hr, hi_, carry, prefix);
        k_out<CPLX><<<g, blk, 0, stream>>>(
            x, phr, phi, pir, pii, prefix, out);
    } else {
        k_serial<CPLX><<<dim3((BATCH * DIM + 255) / 256), dim3(256), 0, stream>>>(
            x, phr, phi, pir, pii, hr, hi_, out);
    }
}

extern "C" void kernel_launch(void* const* d_in, const int* in_sizes, int n_in,
                              void* d_out, int out_size, void* d_ws, size_t ws_size,
                              hipStream_t stream) {
    const float* x   = (const float*)d_in[0];
    const float* hr  = (const float*)d_in[1];
    const float* hi_ = (const float*)d_in[2];
    const float* phr = (const float*)d_in[3];
    const float* phi = (const float*)d_in[4];
    const float* pir = (const float*)d_in[5];
    const float* pii = (const float*)d_in[6];
    float* out = (float*)d_out;

    const size_t total = (size_t)BATCH * SEQ * DIM;
    // out_size >= 2*total  -> buffer holds interleaved complex64 (re,im pairs)
    // otherwise            -> buffer holds exactly total floats: write real part
    if ((size_t)out_size >= 2 * total)
        dispatch<true >(x, hr, hi_, phr, phi, pir, pii, out, d_ws, ws_size, stream);
    else
        dispatch<false>(x, hr, hi_, phr, phi, pir, pii, out, d_ws, ws_size, stream);
}